// Round 1
// baseline (71.392 us; speedup 1.0000x reference)
//
#include <hip/hip_runtime.h>

#define K_OFF 27
#define CIN   2
#define COUT  16
#define BLK   256

__global__ __launch_bounds__(BLK) void spconv_gather_kernel(
    const float* __restrict__ feats,   // [N][2]
    const float* __restrict__ w,       // [27][2][16]
    const int*   __restrict__ nbr,     // [N][27]
    float*       __restrict__ out,     // [N][16]
    int n_pts)
{
    __shared__ int s_nbr[BLK * K_OFF];   // 27648 B

    const int tid     = threadIdx.x;
    const int base_pt = blockIdx.x * BLK;
    const int gbase   = base_pt * K_OFF;
    const int total   = n_pts * K_OFF;

    // Coalesced stage of this block's nbr rows into LDS.
    #pragma unroll
    for (int j = 0; j < K_OFF; ++j) {
        int i = tid + j * BLK;
        int g = gbase + i;
        s_nbr[i] = (g < total) ? nbr[g] : -1;
    }
    __syncthreads();

    float acc[COUT];
    #pragma unroll
    for (int d = 0; d < COUT; ++d) acc[d] = 0.f;

    for (int k = 0; k < K_OFF; ++k) {
        const int idx = s_nbr[tid * K_OFF + k];
        float fx = 0.f, fy = 0.f;
        if (idx >= 0) {
            const float2 f = *reinterpret_cast<const float2*>(feats + (size_t)idx * CIN);
            fx = f.x; fy = f.y;
        }
        const float* wk = w + k * (CIN * COUT);   // uniform address -> s_load
        #pragma unroll
        for (int d = 0; d < COUT; ++d) {
            acc[d] = fmaf(fx, wk[d],        acc[d]);
            acc[d] = fmaf(fy, wk[COUT + d], acc[d]);
        }
    }

    const int n = base_pt + tid;
    if (n < n_pts) {
        float4* o = reinterpret_cast<float4*>(out + (size_t)n * COUT);
        o[0] = make_float4(acc[0],  acc[1],  acc[2],  acc[3]);
        o[1] = make_float4(acc[4],  acc[5],  acc[6],  acc[7]);
        o[2] = make_float4(acc[8],  acc[9],  acc[10], acc[11]);
        o[3] = make_float4(acc[12], acc[13], acc[14], acc[15]);
    }
}

extern "C" void kernel_launch(void* const* d_in, const int* in_sizes, int n_in,
                              void* d_out, int out_size, void* d_ws, size_t ws_size,
                              hipStream_t stream) {
    const float* feats = (const float*)d_in[0];
    const float* w     = (const float*)d_in[1];
    const int*   nbr   = (const int*)d_in[2];
    float*       out   = (float*)d_out;

    const int n_pts = in_sizes[0] / CIN;
    const int grid  = (n_pts + BLK - 1) / BLK;

    spconv_gather_kernel<<<grid, BLK, 0, stream>>>(feats, w, nbr, out, n_pts);
}

// Round 2
// 65.272 us; speedup vs baseline: 1.0938x; 1.0938x over previous
//
#include <hip/hip_runtime.h>

#define K_OFF 27
#define CIN   2
#define COUT  16
#define BLK   256
#define INTS_PER_BLK (BLK * K_OFF)        // 6912
#define INT4_PER_BLK (INTS_PER_BLK / 4)   // 1728
#define CHUNK 9

__global__ __launch_bounds__(BLK) void spconv_gather_kernel(
    const float* __restrict__ feats,   // [N][2]
    const float* __restrict__ w,       // [27][2][16]
    const int*   __restrict__ nbr,     // [N][27]
    float*       __restrict__ out,     // [N][16]
    int n_pts)
{
    __shared__ int s_nbr[INTS_PER_BLK];  // 27648 B

    const int tid     = threadIdx.x;
    const int base_pt = blockIdx.x * BLK;
    const long long gbase      = (long long)base_pt * K_OFF;       // int offset
    const long long total_ints = (long long)n_pts * K_OFF;         // divisible by 4 granularity handled below

    // ---- Coalesced int4 stage of this block's nbr rows into LDS ----
    const int4* nbr4 = reinterpret_cast<const int4*>(nbr + gbase);
    int4*       s4   = reinterpret_cast<int4*>(s_nbr);
    #pragma unroll
    for (int j = 0; j < INT4_PER_BLK / BLK; ++j) {   // 6 full rounds
        const int i = tid + j * BLK;
        const long long g = gbase + (long long)i * 4;
        s4[i] = (g + 3 < total_ints) ? nbr4[i] : make_int4(-1, -1, -1, -1);
    }
    {   // remainder round: 1728 - 6*256 = 192 int4
        const int i = tid + 6 * BLK;
        if (i < INT4_PER_BLK) {
            const long long g = gbase + (long long)i * 4;
            s4[i] = (g + 3 < total_ints) ? nbr4[i] : make_int4(-1, -1, -1, -1);
        }
    }
    __syncthreads();

    float acc[COUT];
    #pragma unroll
    for (int d = 0; d < COUT; ++d) acc[d] = 0.f;

    const float2* feats2 = reinterpret_cast<const float2*>(feats);
    const int row = tid * K_OFF;

    #pragma unroll
    for (int kb = 0; kb < K_OFF; kb += CHUNK) {
        // Phase 1: issue all CHUNK gathers (unconditional, clamped) before any use.
        float2 f[CHUNK];
        float  m[CHUNK];
        #pragma unroll
        for (int j = 0; j < CHUNK; ++j) {
            const int idx  = s_nbr[row + kb + j];        // stride-27: bank-conflict-free
            m[j] = (idx >= 0) ? 1.0f : 0.0f;
            const int safe = (idx > 0) ? idx : 0;        // invalid lanes broadcast line 0
            f[j] = feats2[safe];
        }
        // Phase 2: FMAs (weights via uniform address -> scalar loads)
        #pragma unroll
        for (int j = 0; j < CHUNK; ++j) {
            const float fx = f[j].x * m[j];
            const float fy = f[j].y * m[j];
            const float* wk = w + (kb + j) * (CIN * COUT);
            #pragma unroll
            for (int d = 0; d < COUT; ++d) {
                acc[d] = fmaf(fx, wk[d],        acc[d]);
                acc[d] = fmaf(fy, wk[COUT + d], acc[d]);
            }
        }
    }

    const int n = base_pt + tid;
    if (n < n_pts) {
        float4* o = reinterpret_cast<float4*>(out + (size_t)n * COUT);
        o[0] = make_float4(acc[0],  acc[1],  acc[2],  acc[3]);
        o[1] = make_float4(acc[4],  acc[5],  acc[6],  acc[7]);
        o[2] = make_float4(acc[8],  acc[9],  acc[10], acc[11]);
        o[3] = make_float4(acc[12], acc[13], acc[14], acc[15]);
    }
}

extern "C" void kernel_launch(void* const* d_in, const int* in_sizes, int n_in,
                              void* d_out, int out_size, void* d_ws, size_t ws_size,
                              hipStream_t stream) {
    const float* feats = (const float*)d_in[0];
    const float* w     = (const float*)d_in[1];
    const int*   nbr   = (const int*)d_in[2];
    float*       out   = (float*)d_out;

    const int n_pts = in_sizes[0] / CIN;
    const int grid  = (n_pts + BLK - 1) / BLK;

    spconv_gather_kernel<<<grid, BLK, 0, stream>>>(feats, w, nbr, out, n_pts);
}

// Round 3
// 64.016 us; speedup vs baseline: 1.1152x; 1.0196x over previous
//
#include <hip/hip_runtime.h>

#define K_OFF 27
#define CIN   2
#define COUT  16
#define BLK   256
#define CH    9

__global__ __launch_bounds__(BLK) void spconv_gather_kernel(
    const float* __restrict__ feats,   // [N][2]
    const float* __restrict__ w,       // [27][2][16]
    const int*   __restrict__ nbr,     // [N][27]
    float*       __restrict__ out,     // [N][16]
    int n_pts)
{
    __shared__ int s_nbr[BLK * K_OFF];   // 27648 B; wave-partitioned

    const int tid     = threadIdx.x;
    const int lane    = tid & 63;
    const int wv      = tid >> 6;
    const int base_pt = blockIdx.x * BLK;
    const int wpt     = base_pt + wv * 64;            // this wave's first point

    int* sw = s_nbr + wv * (64 * K_OFF);              // wave-private 6912 B
    const long long g0         = (long long)wpt * K_OFF;
    const long long total_ints = (long long)n_pts * K_OFF;

    // ---- wave-local coalesced int4 stage (no block barrier needed) ----
    int4*       sw4 = reinterpret_cast<int4*>(sw);
    const int4* g4  = reinterpret_cast<const int4*>(nbr + g0);   // 16B-aligned: wpt*27*4 % 16 == 0
    #pragma unroll
    for (int j = 0; j < 7; ++j) {
        const int i = lane + j * 64;
        if (i < (64 * K_OFF) / 4) {                   // 432 int4
            const long long g = g0 + (long long)i * 4;
            sw4[i] = (g + 3 < total_ints) ? g4[i] : make_int4(-1, -1, -1, -1);
        }
    }
    // same-wave producer/consumer: lockstep + LDS op drain is sufficient
    asm volatile("s_waitcnt lgkmcnt(0)" ::: "memory");
    __builtin_amdgcn_wave_barrier();

    const float2* feats2 = reinterpret_cast<const float2*>(feats);
    const int row = lane * K_OFF;

    auto issue = [&](int kb, float2* f, float* m) {
        #pragma unroll
        for (int j = 0; j < CH; ++j) {
            const int idx = sw[row + kb + j];         // stride-27 ints: conflict-free
            m[j] = (idx >= 0) ? 1.0f : 0.0f;
            f[j] = feats2[idx > 0 ? idx : 0];         // invalid lanes broadcast line 0
        }
    };
    float acc[COUT];
    #pragma unroll
    for (int d = 0; d < COUT; ++d) acc[d] = 0.f;

    auto fma9 = [&](int kb, const float2* f, const float* m) {
        #pragma unroll
        for (int j = 0; j < CH; ++j) {
            const float fx = f[j].x * m[j];
            const float fy = f[j].y * m[j];
            const float* wk = w + (kb + j) * (CIN * COUT);  // uniform -> s_load
            #pragma unroll
            for (int d = 0; d < COUT; ++d) {
                acc[d] = fmaf(fx, wk[d],        acc[d]);
                acc[d] = fmaf(fy, wk[COUT + d], acc[d]);
            }
        }
    };

    // ---- 3-chunk rotated software pipeline: 18 gathers in flight before 1st FMA ----
    float2 fA[CH], fB[CH];
    float  mA[CH], mB[CH];
    issue(0,  fA, mA);
    issue(CH, fB, mB);
    fma9(0, fA, mA);
    issue(2 * CH, fA, mA);     // in flight during fma of chunk B
    fma9(CH, fB, mB);
    fma9(2 * CH, fA, mA);

    const int n = base_pt + tid;
    if (n < n_pts) {
        float4* o = reinterpret_cast<float4*>(out + (size_t)n * COUT);
        o[0] = make_float4(acc[0],  acc[1],  acc[2],  acc[3]);
        o[1] = make_float4(acc[4],  acc[5],  acc[6],  acc[7]);
        o[2] = make_float4(acc[8],  acc[9],  acc[10], acc[11]);
        o[3] = make_float4(acc[12], acc[13], acc[14], acc[15]);
    }
}

extern "C" void kernel_launch(void* const* d_in, const int* in_sizes, int n_in,
                              void* d_out, int out_size, void* d_ws, size_t ws_size,
                              hipStream_t stream) {
    const float* feats = (const float*)d_in[0];
    const float* w     = (const float*)d_in[1];
    const int*   nbr   = (const int*)d_in[2];
    float*       out   = (float*)d_out;

    const int n_pts = in_sizes[0] / CIN;
    const int grid  = (n_pts + BLK - 1) / BLK;

    spconv_gather_kernel<<<grid, BLK, 0, stream>>>(feats, w, nbr, out, n_pts);
}